// Round 15
// baseline (106.077 us; speedup 1.0000x reference)
//
#include <hip/hip_runtime.h>
#include <hip/hip_bf16.h>
#include <stdint.h>

// ---- problem constants ----
#define NCLS   19
#define CACHE  5000
#define NT32   157            // 32-col windows per class (157*32 = 5024, 24 pad cols)
#define DDIM   256
#define NANCH  102
#define NVIEW  10
#define NROWS  1020
#define NSUB   13             // column sub-chunks per class
#define NCHUNK (NCLS*NSUB)    // 247
#define NWG    (4*NCHUNK)     // 988 pass1 blocks
#define SCALE_A 20.6099319733f   // (1/0.07) * log2(e): MFMA acc = s * log2(e)
#define LN2     0.69314718056f

using bf16x8 = __attribute__((ext_vector_type(8))) __bf16;
using f32x4  = __attribute__((ext_vector_type(4))) float;

#if __has_builtin(__builtin_amdgcn_exp2f)
#define EXP2(x) __builtin_amdgcn_exp2f(x)
#else
#define EXP2(x) __expf((x) * LN2)
#endif

static __device__ __forceinline__ unsigned short f2bf(float x) {
    unsigned int u = __float_as_uint(x);
    unsigned int r = (u + 0x7FFFu + ((u >> 16) & 1u)) >> 16;
    return (unsigned short)r;
}

// Raw barrier WITHOUT the vmcnt(0) drain __syncthreads emits (m97/m233):
// lgkmcnt(0) publishes ds_writes; sched_barrier fences pin ordering (rule #18).
#define BARRIER_NODRAIN() do {                                   \
        asm volatile("s_waitcnt lgkmcnt(0)" ::: "memory");       \
        __builtin_amdgcn_sched_barrier(0);                       \
        __builtin_amdgcn_s_barrier();                            \
        __builtin_amdgcn_sched_barrier(0);                       \
    } while (0)

// ---- anchors: view-major [1024][256] bf16, pre-scaled by (1/T)*log2(e) ----
__global__ __launch_bounds__(256) void conv_anchor2(const float* __restrict__ X,
                                                    unsigned short* __restrict__ Abf) {
    int n = blockIdx.x;     // 0..1023
    int k = threadIdx.x;    // 0..255
    float v = 0.f;
    if (n < NROWS) {
        int vv = n / NANCH, a = n - vv * NANCH;
        v = X[((size_t)a * NVIEW + vv) * DDIM + k] * SCALE_A;
    }
    Abf[(size_t)n * DDIM + k] = f2bf(v);
}

// ---- fused pass: 32-col windows = 2x 16-col sub-tiles per barrier ----
// R10 structure with doubled window width: per window, stage 32 cols of f32
// (8 dwordx4/thread), cvt, ds_write into two 8KB half-tiles (R10's XOR map
// per half), then 2 sequential 16-col COMPUTE passes (bfrag regs reused).
// Half the barriers/convoys per MFMA vs TW=16.
__global__ __launch_bounds__(256, 2) void pass1_kernel(
    const unsigned short* __restrict__ Abf, const float* __restrict__ Qf,
    const int* __restrict__ y,
    float* __restrict__ Pt, float* __restrict__ Pe, float* __restrict__ Ps)
{
    __shared__ unsigned char lds[2][16384];   // 2 buffers x (2 x 8KB half-tiles)

    // bijective XCD swizzle (m204): nwg=988, 8 XCDs, q=123, r=4.
    // rt-minor: all 4 row-tiles of a column chunk share an XCD/L2.
    int orig = blockIdx.x;
    int xcd = orig & 7, slot = orig >> 3;
    int wid = (xcd < 4 ? xcd * 124 : 496 + (xcd - 4) * 123) + slot;
    int rt = wid & 3;           // row tile (256 rows)
    int cs = wid >> 2;          // 0..246 column chunk
    int cls = cs / NSUB;
    int sub = cs - cls * NSUB;
    int t0 = (NT32 * sub) / NSUB, t1 = (NT32 * (sub + 1)) / NSUB;

    int tid = threadIdx.x;
    int wave = tid >> 6, lane = tid & 63;
    int lg = lane >> 4, lm = lane & 15;
    int wrb = rt * 256 + wave * 64;   // this wave owns rows [wrb, wrb+64)

    // stage-thread mapping (R10 map, applied per 16-col half):
    int c   = tid >> 4;        // 0..15: col within half-tile
    int seg = tid & 15;        // 16-float segment within the col
    int skk = seg >> 1;        // chunk kk this thread feeds
    int sidx0 = skk * 64 + ((seg & 1) * 2) * 16 + c;
    unsigned sb0 = (unsigned)(sidx0 * 16) ^ (unsigned)(skk << 4);
    unsigned sb1 = (unsigned)((sidx0 + 16) * 16) ^ (unsigned)(skk << 4);
    const float* qbase = Qf + (size_t)cls * CACHE * DDIM + seg * 16;

    // A fragments (log2-scaled): frag f covers rows wrb+f*16, row-in-frag = lane&15
    bf16x8 afrag[4][8];
    #pragma unroll
    for (int f = 0; f < 4; ++f)
        #pragma unroll
        for (int kk = 0; kk < 8; ++kk)
            afrag[f][kk] = *reinterpret_cast<const bf16x8*>(
                Abf + (size_t)(wrb + f * 16 + lm) * DDIM + kk * 32 + lg * 8);

    float tacc[4][4] = {}, sacc[4][4] = {};

    // staging registers: half 0 -> s_a*, half 1 -> s_b* (named, static)
    f32x4 s_a0, s_a1, s_a2, s_a3, s_b0, s_b1, s_b2, s_b3;
    bool ok_a, ok_b;

#define SLOAD(t) do {                                                         \
        int _ca = (t) * 32 + c;                                               \
        int _cb = _ca + 16;                                                   \
        ok_a = _ca < CACHE; ok_b = _cb < CACHE;                               \
        const f32x4* _pa = reinterpret_cast<const f32x4*>(                    \
            qbase + (size_t)(ok_a ? _ca : CACHE - 1) * DDIM);                 \
        const f32x4* _pb = reinterpret_cast<const f32x4*>(                    \
            qbase + (size_t)(ok_b ? _cb : CACHE - 1) * DDIM);                 \
        s_a0 = _pa[0]; s_a1 = _pa[1]; s_a2 = _pa[2]; s_a3 = _pa[3];           \
        s_b0 = _pb[0]; s_b1 = _pb[1]; s_b2 = _pb[2]; s_b3 = _pb[3];           \
    } while (0)

#define CVT1(r0, r1, r2, r3, okv, base) do {                                  \
        bf16x8 _p0, _p1;                                                      \
        _Pragma("unroll")                                                     \
        for (int j = 0; j < 4; ++j) {                                         \
            _p0[j]     = (__bf16)r0[j];                                       \
            _p0[j + 4] = (__bf16)r1[j];                                       \
            _p1[j]     = (__bf16)r2[j];                                       \
            _p1[j + 4] = (__bf16)r3[j];                                       \
        }                                                                     \
        bf16x8 _z = {};                                                       \
        if (!okv) { _p0 = _z; _p1 = _z; }                                     \
        *reinterpret_cast<bf16x8*>(&(base)[sb0]) = _p0;                       \
        *reinterpret_cast<bf16x8*>(&(base)[sb1]) = _p1;                       \
    } while (0)

#define CVTWRITE(buf) do {                                                    \
        CVT1(s_a0, s_a1, s_a2, s_a3, ok_a, &lds[buf][0]);                     \
        CVT1(s_b0, s_b1, s_b2, s_b3, ok_b, &lds[buf][8192]);                  \
    } while (0)

#define COMPUTE(buf, half) do {                                               \
        bf16x8 bfrag[8];                                                      \
        _Pragma("unroll")                                                     \
        for (int kk = 0; kk < 8; ++kk)                                        \
            bfrag[kk] = *reinterpret_cast<const bf16x8*>(                     \
                &lds[buf][(half) * 8192 +                                     \
                    ((unsigned)((kk * 64 + lane) * 16) ^ (unsigned)(kk << 4))]); \
        f32x4 acc[4];                                                         \
        _Pragma("unroll")                                                     \
        for (int f = 0; f < 4; ++f) acc[f] = (f32x4){0.f, 0.f, 0.f, 0.f};     \
        _Pragma("unroll")                                                     \
        for (int kk = 0; kk < 8; ++kk)                                        \
            _Pragma("unroll")                                                 \
            for (int f = 0; f < 4; ++f)                                       \
                acc[f] = __builtin_amdgcn_mfma_f32_16x16x32_bf16(             \
                    afrag[f][kk], bfrag[kk], acc[f], 0, 0, 0);                \
        _Pragma("unroll")                                                     \
        for (int f = 0; f < 4; ++f)                                           \
            _Pragma("unroll")                                                 \
            for (int r = 0; r < 4; ++r) {                                     \
                float v = acc[f][r];            /* s * log2(e) */             \
                tacc[f][r] += EXP2(v);          /* pad cols: v=0 -> e=1 */    \
                sacc[f][r] += v;                                              \
            }                                                                 \
    } while (0)

    int nt = t1 - t0;

    // prologue: stage window 0 into buf 0
    SLOAD(t0);
    CVTWRITE(0);
    BARRIER_NODRAIN();

    int cur = 0;
    for (int it = 0; it < nt; ++it) {
        if (it + 1 < nt) SLOAD(t0 + it + 1);   // 8 loads fly across the window
        COMPUTE(cur, 0);
        COMPUTE(cur, 1);
        if (it + 1 < nt) CVTWRITE(cur ^ 1);    // reg-dep vmcnt wait sinks here
        BARRIER_NODRAIN();
        cur ^= 1;
    }
#undef SLOAD
#undef CVT1
#undef CVTWRITE
#undef COMPUTE

    // reduce across the 16 column-lanes (lm) and store per-chunk partials
    #pragma unroll
    for (int f = 0; f < 4; ++f)
        #pragma unroll
        for (int r = 0; r < 4; ++r) {
            float t = tacc[f][r], s = sacc[f][r];
            #pragma unroll
            for (int m = 1; m < 16; m <<= 1) {
                t += __shfl_xor(t, m);
                s += __shfl_xor(s, m);
            }
            if (lm == 0) {
                int row = wrb + f * 16 + lg * 4 + r;
                float mp = (row < NROWS && y[row % NANCH] == cls) ? 1.0f : 0.0f;
                size_t idx = (size_t)cs * 1024 + row;
                Pt[idx] = t; Pe[idx] = mp * t; Ps[idx] = mp * s;
            }
        }
}

// ---- per-row finalization: 16 blocks x 256 thr, 4 threads per row ----
__global__ __launch_bounds__(256) void reduce_rows(const float* __restrict__ Pt,
                                                   const float* __restrict__ Pe,
                                                   const float* __restrict__ Ps,
                                                   float* __restrict__ rowloss) {
    int tid = threadIdx.x;
    int row = blockIdx.x * 64 + (tid >> 2);   // 0..1023
    int part = tid & 3;
    float tot = 0.f, pe = 0.f, ps = 0.f;
    for (int c = part; c < NCHUNK; c += 4) {
        size_t idx = (size_t)c * 1024 + row;
        tot += Pt[idx]; pe += Pe[idx]; ps += Ps[idx];
    }
    tot += __shfl_xor(tot, 1); pe += __shfl_xor(pe, 1); ps += __shfl_xor(ps, 1);
    tot += __shfl_xor(tot, 2); pe += __shfl_xor(pe, 2); ps += __shfl_xor(ps, 2);
    if (part == 0) {
        float r = 0.f;
        if (row < NROWS) {
            // 24 pad cols/class (5024-5000): tot has 19*24=456 pads, pe has 24.
            float ns    = tot - pe - 432.0f;        // sum exp over true negatives
            float pos_e = pe - 24.0f;               // sum exp over true positives
            float pos_s = ps * LN2;                 // sum of s over positives (ln domain)
            // sum_pos log(e^s + ns) ~= 5000*log(ns) + pos_e/ns   (first-order log1p)
            float sum_logprob = pos_s - (5000.0f * logf(ns) + pos_e / ns);
            r = -sum_logprob / (5000.0f + 1e-4f);
        }
        rowloss[row] = r;
    }
}

// ---- final mean over 1020 rows ----
__global__ __launch_bounds__(256) void pass3_kernel(const float* __restrict__ rowloss,
                                                    float* __restrict__ out) {
    float local = 0.f;
    for (int n = threadIdx.x; n < 1024; n += 256) local += rowloss[n];
    #pragma unroll
    for (int m = 1; m < 64; m <<= 1) local += __shfl_xor(local, m);
    __shared__ float sb[4];
    if ((threadIdx.x & 63) == 0) sb[threadIdx.x >> 6] = local;
    __syncthreads();
    if (threadIdx.x == 0)
        out[0] = (sb[0] + sb[1] + sb[2] + sb[3]) * (1.0f / (float)NROWS);
}

extern "C" void kernel_launch(void* const* d_in, const int* in_sizes, int n_in,
                              void* d_out, int out_size, void* d_ws, size_t ws_size,
                              hipStream_t stream) {
    const float* X  = (const float*)d_in[0];   // [102][10][256]
    const int*   y  = (const int*)d_in[1];     // [102]
    const float* Qf = (const float*)d_in[2];   // [19][5000][256]
    float* out = (float*)d_out;

    char* ws = (char*)d_ws;
    // ws layout (bytes):
    //   Abf [1024][256] bf16           :    524,288
    //   Pt  [247][1024] f32            :  1,011,712
    //   Pe  [247][1024] f32            :  1,011,712
    //   Ps  [247][1024] f32            :  1,011,712
    //   rowloss [1024] f32             :      4,096
    unsigned short* Abf = (unsigned short*)(ws);
    float* Pt      = (float*)(ws + 524288);
    float* Pe      = (float*)(ws + 1536000);
    float* Ps      = (float*)(ws + 2547712);
    float* rowloss = (float*)(ws + 3559424);

    conv_anchor2<<<1024, 256, 0, stream>>>(X, Abf);
    pass1_kernel<<<NWG, 256, 0, stream>>>(Abf, Qf, y, Pt, Pe, Ps);  // 988 blocks
    reduce_rows<<<16, 256, 0, stream>>>(Pt, Pe, Ps, rowloss);
    pass3_kernel<<<1, 256, 0, stream>>>(rowloss, out);
}

// Round 16
// 101.808 us; speedup vs baseline: 1.0419x; 1.0419x over previous
//
#include <hip/hip_runtime.h>
#include <hip/hip_bf16.h>
#include <stdint.h>

// ---- problem constants ----
#define NCLS   19
#define CACHE  5000
#define NTILE  313            // 16-col tiles per class (313*16 = 5008, 8 pad cols)
#define DDIM   256
#define NANCH  102
#define NVIEW  10
#define NROWS  1020
#define NSUB   13             // column sub-chunks per class
#define NCHUNK (NCLS*NSUB)    // 247
#define NWG    (4*NCHUNK)     // 988 pass1 blocks
#define SCALE_A 20.6099319733f   // (1/0.07) * log2(e): MFMA acc = s * log2(e)
#define LN2     0.69314718056f

using bf16x8 = __attribute__((ext_vector_type(8))) __bf16;
using f32x4  = __attribute__((ext_vector_type(4))) float;

#if __has_builtin(__builtin_amdgcn_exp2f)
#define EXP2(x) __builtin_amdgcn_exp2f(x)
#else
#define EXP2(x) __expf((x) * LN2)
#endif

static __device__ __forceinline__ unsigned short f2bf(float x) {
    unsigned int u = __float_as_uint(x);
    unsigned int r = (u + 0x7FFFu + ((u >> 16) & 1u)) >> 16;
    return (unsigned short)r;
}

// Raw barrier WITHOUT the vmcnt(0) drain __syncthreads emits (m97/m233).
#define BARRIER_NODRAIN() do {                                   \
        asm volatile("s_waitcnt lgkmcnt(0)" ::: "memory");       \
        __builtin_amdgcn_sched_barrier(0);                       \
        __builtin_amdgcn_s_barrier();                            \
        __builtin_amdgcn_sched_barrier(0);                       \
    } while (0)

// ---- anchors: view-major [1024][256] bf16, pre-scaled by (1/T)*log2(e) ----
__global__ __launch_bounds__(256) void conv_anchor2(const float* __restrict__ X,
                                                    unsigned short* __restrict__ Abf) {
    int n = blockIdx.x;     // 0..1023
    int k = threadIdx.x;    // 0..255
    float v = 0.f;
    if (n < NROWS) {
        int vv = n / NANCH, a = n - vv * NANCH;
        v = X[((size_t)a * NVIEW + vv) * DDIM + k] * SCALE_A;
    }
    Abf[(size_t)n * DDIM + k] = f2bf(v);
}

// ---- fused pass: R10/R14 structure + DISTANCE-2 staging prefetch ----
// Window it: SLOAD(t+2) into the reg set freed two windows ago; COMPUTE(cur);
// CVTWRITE the set loaded last window into the other LDS buffer. Load->use
// distance = 2 windows (~1200+ cyc) > HBM latency (~900, m126). Two named
// reg sets (A/B), statically indexed (rule #20).
__global__ __launch_bounds__(256, 2) void pass1_kernel(
    const unsigned short* __restrict__ Abf, const float* __restrict__ Qf,
    const int* __restrict__ y,
    float* __restrict__ Pt, float* __restrict__ Pe, float* __restrict__ Ps)
{
    __shared__ unsigned char lds[2][8192];   // 2 x 8KB bf16 fragment tiles

    // bijective XCD swizzle (m204): nwg=988, 8 XCDs, q=123, r=4.
    int orig = blockIdx.x;
    int xcd = orig & 7, slot = orig >> 3;
    int wid = (xcd < 4 ? xcd * 124 : 496 + (xcd - 4) * 123) + slot;
    int rt = wid & 3;           // row tile (256 rows)
    int cs = wid >> 2;          // 0..246 column chunk
    int cls = cs / NSUB;
    int sub = cs - cls * NSUB;
    int t0 = (NTILE * sub) / NSUB, t1 = (NTILE * (sub + 1)) / NSUB;

    int tid = threadIdx.x;
    int wave = tid >> 6, lane = tid & 63;
    int lg = lane >> 4, lm = lane & 15;
    int wrb = rt * 256 + wave * 64;   // this wave owns rows [wrb, wrb+64)

    // stage-thread mapping (R10): col c = tid>>4, 64B f32 segment seg = tid&15
    int c   = tid >> 4;
    int seg = tid & 15;
    int skk = seg >> 1;
    int sidx0 = skk * 64 + ((seg & 1) * 2) * 16 + c;
    unsigned sb0 = (unsigned)(sidx0 * 16) ^ (unsigned)(skk << 4);
    unsigned sb1 = (unsigned)((sidx0 + 16) * 16) ^ (unsigned)(skk << 4);
    const float* qbase = Qf + (size_t)cls * CACHE * DDIM + seg * 16;

    // A fragments (log2-scaled)
    bf16x8 afrag[4][8];
    #pragma unroll
    for (int f = 0; f < 4; ++f)
        #pragma unroll
        for (int kk = 0; kk < 8; ++kk)
            afrag[f][kk] = *reinterpret_cast<const bf16x8*>(
                Abf + (size_t)(wrb + f * 16 + lm) * DDIM + kk * 32 + lg * 8);

    float tacc[4][4] = {}, sacc[4][4] = {};

    // two named staging reg sets
    f32x4 sA0, sA1, sA2, sA3, sB0, sB1, sB2, sB3;
    bool okA, okB;

#define SLOAD1(R0, R1, R2, R3, OK, t) do {                                    \
        int _col = (t) * 16 + c;                                              \
        OK = _col < CACHE;                                                    \
        const f32x4* _src = reinterpret_cast<const f32x4*>(                   \
            qbase + (size_t)(OK ? _col : CACHE - 1) * DDIM);                  \
        R0 = _src[0]; R1 = _src[1]; R2 = _src[2]; R3 = _src[3];               \
    } while (0)

#define CVTW1(R0, R1, R2, R3, OK, buf) do {                                   \
        bf16x8 _p0, _p1;                                                      \
        _Pragma("unroll")                                                     \
        for (int j = 0; j < 4; ++j) {                                         \
            _p0[j]     = (__bf16)R0[j];                                       \
            _p0[j + 4] = (__bf16)R1[j];                                       \
            _p1[j]     = (__bf16)R2[j];                                       \
            _p1[j + 4] = (__bf16)R3[j];                                       \
        }                                                                     \
        bf16x8 _z = {};                                                       \
        if (!OK) { _p0 = _z; _p1 = _z; }                                      \
        *reinterpret_cast<bf16x8*>(&lds[buf][sb0]) = _p0;                     \
        *reinterpret_cast<bf16x8*>(&lds[buf][sb1]) = _p1;                     \
    } while (0)

#define COMPUTE(buf) do {                                                     \
        bf16x8 bfrag[8];                                                      \
        _Pragma("unroll")                                                     \
        for (int kk = 0; kk < 8; ++kk)                                        \
            bfrag[kk] = *reinterpret_cast<const bf16x8*>(                     \
                &lds[buf][(unsigned)((kk * 64 + lane) * 16) ^ (unsigned)(kk << 4)]); \
        f32x4 acc[4];                                                         \
        _Pragma("unroll")                                                     \
        for (int f = 0; f < 4; ++f) acc[f] = (f32x4){0.f, 0.f, 0.f, 0.f};     \
        _Pragma("unroll")                                                     \
        for (int kk = 0; kk < 8; ++kk)                                        \
            _Pragma("unroll")                                                 \
            for (int f = 0; f < 4; ++f)                                       \
                acc[f] = __builtin_amdgcn_mfma_f32_16x16x32_bf16(             \
                    afrag[f][kk], bfrag[kk], acc[f], 0, 0, 0);                \
        _Pragma("unroll")                                                     \
        for (int f = 0; f < 4; ++f)                                           \
            _Pragma("unroll")                                                 \
            for (int r = 0; r < 4; ++r) {                                     \
                float v = acc[f][r];            /* s * log2(e) */             \
                tacc[f][r] += EXP2(v);          /* pad cols: v=0 -> e=1 */    \
                sacc[f][r] += v;                                              \
            }                                                                 \
    } while (0)

#define SLOADA(t) SLOAD1(sA0, sA1, sA2, sA3, okA, t)
#define SLOADB(t) SLOAD1(sB0, sB1, sB2, sB3, okB, t)
#define CVTWRITEA(buf) CVTW1(sA0, sA1, sA2, sA3, okA, buf)
#define CVTWRITEB(buf) CVTW1(sB0, sB1, sB2, sB3, okB, buf)

    int nt = t1 - t0;

    // prologue: window 0 staged via A; window 1 preloaded into B
    SLOADA(t0);
    CVTWRITEA(0);
    if (nt > 1) SLOADB(t0 + 1);
    BARRIER_NODRAIN();

    int cur = 0, it = 0;
    for (;;) {
        // even-position window: prefetch t+2 into A (freed 2 windows ago),
        // compute current, publish B (loaded last window) into next buffer.
        if (it + 2 < nt) SLOADA(t0 + it + 2);
        COMPUTE(cur);
        if (it + 1 < nt) CVTWRITEB(cur ^ 1);
        BARRIER_NODRAIN();
        cur ^= 1; ++it;
        if (it >= nt) break;

        if (it + 2 < nt) SLOADB(t0 + it + 2);
        COMPUTE(cur);
        if (it + 1 < nt) CVTWRITEA(cur ^ 1);
        BARRIER_NODRAIN();
        cur ^= 1; ++it;
        if (it >= nt) break;
    }
#undef SLOAD1
#undef CVTW1
#undef COMPUTE
#undef SLOADA
#undef SLOADB
#undef CVTWRITEA
#undef CVTWRITEB

    // reduce across the 16 column-lanes (lm) and store per-chunk partials
    #pragma unroll
    for (int f = 0; f < 4; ++f)
        #pragma unroll
        for (int r = 0; r < 4; ++r) {
            float t = tacc[f][r], s = sacc[f][r];
            #pragma unroll
            for (int m = 1; m < 16; m <<= 1) {
                t += __shfl_xor(t, m);
                s += __shfl_xor(s, m);
            }
            if (lm == 0) {
                int row = wrb + f * 16 + lg * 4 + r;
                float mp = (row < NROWS && y[row % NANCH] == cls) ? 1.0f : 0.0f;
                size_t idx = (size_t)cs * 1024 + row;
                Pt[idx] = t; Pe[idx] = mp * t; Ps[idx] = mp * s;
            }
        }
}

// ---- per-row finalization: 16 blocks x 256 thr, 4 threads per row ----
__global__ __launch_bounds__(256) void reduce_rows(const float* __restrict__ Pt,
                                                   const float* __restrict__ Pe,
                                                   const float* __restrict__ Ps,
                                                   float* __restrict__ rowloss) {
    int tid = threadIdx.x;
    int row = blockIdx.x * 64 + (tid >> 2);   // 0..1023
    int part = tid & 3;
    float tot = 0.f, pe = 0.f, ps = 0.f;
    for (int c = part; c < NCHUNK; c += 4) {
        size_t idx = (size_t)c * 1024 + row;
        tot += Pt[idx]; pe += Pe[idx]; ps += Ps[idx];
    }
    tot += __shfl_xor(tot, 1); pe += __shfl_xor(pe, 1); ps += __shfl_xor(ps, 1);
    tot += __shfl_xor(tot, 2); pe += __shfl_xor(pe, 2); ps += __shfl_xor(ps, 2);
    if (part == 0) {
        float r = 0.f;
        if (row < NROWS) {
            // tot includes all 19*8=152 pad cols (e=1 each); pe the 8 pads of pos class
            float ns    = tot - pe - 144.0f;        // sum exp over true negatives
            float pos_e = pe - 8.0f;                // sum exp over true positives
            float pos_s = ps * LN2;                 // sum of s over positives (ln domain)
            // sum_pos log(e^s + ns) ~= 5000*log(ns) + pos_e/ns   (first-order log1p)
            float sum_logprob = pos_s - (5000.0f * logf(ns) + pos_e / ns);
            r = -sum_logprob / (5000.0f + 1e-4f);
        }
        rowloss[row] = r;
    }
}

// ---- final mean over 1020 rows ----
__global__ __launch_bounds__(256) void pass3_kernel(const float* __restrict__ rowloss,
                                                    float* __restrict__ out) {
    float local = 0.f;
    for (int n = threadIdx.x; n < 1024; n += 256) local += rowloss[n];
    #pragma unroll
    for (int m = 1; m < 64; m <<= 1) local += __shfl_xor(local, m);
    __shared__ float sb[4];
    if ((threadIdx.x & 63) == 0) sb[threadIdx.x >> 6] = local;
    __syncthreads();
    if (threadIdx.x == 0)
        out[0] = (sb[0] + sb[1] + sb[2] + sb[3]) * (1.0f / (float)NROWS);
}

extern "C" void kernel_launch(void* const* d_in, const int* in_sizes, int n_in,
                              void* d_out, int out_size, void* d_ws, size_t ws_size,
                              hipStream_t stream) {
    const float* X  = (const float*)d_in[0];   // [102][10][256]
    const int*   y  = (const int*)d_in[1];     // [102]
    const float* Qf = (const float*)d_in[2];   // [19][5000][256]
    float* out = (float*)d_out;

    char* ws = (char*)d_ws;
    // ws layout (bytes):
    //   Abf [1024][256] bf16           :    524,288
    //   Pt  [247][1024] f32            :  1,011,712
    //   Pe  [247][1024] f32            :  1,011,712
    //   Ps  [247][1024] f32            :  1,011,712
    //   rowloss [1024] f32             :      4,096
    unsigned short* Abf = (unsigned short*)(ws);
    float* Pt      = (float*)(ws + 524288);
    float* Pe      = (float*)(ws + 1536000);
    float* Ps      = (float*)(ws + 2547712);
    float* rowloss = (float*)(ws + 3559424);

    conv_anchor2<<<1024, 256, 0, stream>>>(X, Abf);
    pass1_kernel<<<NWG, 256, 0, stream>>>(Abf, Qf, y, Pt, Pe, Ps);  // 988 blocks
    reduce_rows<<<16, 256, 0, stream>>>(Pt, Pe, Ps, rowloss);
    pass3_kernel<<<1, 256, 0, stream>>>(rowloss, out);
}